// Round 12
// baseline (976.963 us; speedup 1.0000x reference)
//
#include <hip/hip_runtime.h>
#include <cstdint>

// ODEBlock: 16 RK4 steps of f(t,y) = tanh(y@W1 + b1 + t) @ W2 + b2
// B=1024 (M), D=512, H=2048. gemm1 bf16 MFMA; gemm2 fp8-e4m3 MFMA.
// R24 = R23 (877us best) with the occupancy-vs-pipeline point flipped:
// both GEMMs single-buffered (32KB LDS) at 4 blocks/CU instead of
// double-buffered (64KB) at 2 blocks/CU. Mechanism: each kt's barrier
// drains vmcnt(0) for all waves; at 2 blk/CU little co-resident work hides
// it (m97 ~20% stall). 4 blk/CU doubles cross-block TLP (m114: co-resident
// waves overlap fully). Barriers/kt unchanged (2). launch_bounds(256,4)
// caps 128 VGPR (kernels fit). Arithmetic order untouched -> absmax
// bit-identical 0.1015625 (margin 6%, precision levers frozen).
// Also merges transpose x2 + init into one setup kernel (-2 boundaries).
// Proven stack kept: fp8 gemm2 (R23 -213us), XCD swizzles (R20 -55us),
// fused RK4 epilogue (R19 -104us). Mega-kernel line dead (R14-R22:
// cross-block visibility needs full acq/rel wb/inv; absmax 1.9336 x4).
// Decision rule: regression -> revert to R23 dbuf structure.

typedef __bf16 bf16x8 __attribute__((ext_vector_type(8)));
typedef float f32x4 __attribute__((ext_vector_type(4)));

#define AS1 __attribute__((address_space(1)))
#define AS3 __attribute__((address_space(3)))

#define MDIM 1024
#define DDIM 512
#define HDIM 2048

#define GEMM_LDS (32 * 1024)    // gemm1: sA 16KB + sB 16KB (single buf)
#define GEMM2_LDS (32 * 1024)   // gemm2rk4: sA8 16KB + sB8 16KB (single buf)

__device__ __forceinline__ void async_copy16(const void* g, void* lds) {
  __builtin_amdgcn_global_load_lds((const AS1 void*)g, (AS3 void*)lds, 16, 0, 0);
}

__device__ __forceinline__ unsigned short f32_to_bf16(float f) {
  union { float f; unsigned u; } c; c.f = f;
  unsigned u = c.u + 0x7FFFu + ((c.u >> 16) & 1u);   // RNE
  return (unsigned short)(u >> 16);
}

// f32 -> fp8 e4m3 (gfx950 native); duplicated src = byte-order-immune.
__device__ __forceinline__ unsigned char f32_to_fp8(float v) {
  unsigned p;
  asm("v_cvt_pk_fp8_f32 %0, %1, %1" : "=v"(p) : "v"(v));
  return (unsigned char)(p & 0xFF);
}

__device__ __forceinline__ float tanh_fast(float x) {
  float a = __builtin_fabsf(x);
  float e = __expf(-2.0f * a);                        // in (0,1], no overflow
  float r = (1.0f - e) * __builtin_amdgcn_rcpf(1.0f + e);
  return __builtin_copysignf(r, x);
}

// ---- merged setup: W1->W1T bf16, W2->W2T8 fp8, y/arg init -----------------
// blocks 0..255: transpose W1 [512,2048] -> W1T bf16 [2048,512]
// blocks 256..511: transpose W2 [2048,512] -> W2T8 fp8 [512,2048]
// blocks 512..2559: y = x, arg = bf16(x)
__global__ __launch_bounds__(256) void setup_kernel(
    const float* __restrict__ x, float* __restrict__ y,
    unsigned short* __restrict__ arg,
    const float* __restrict__ W1, unsigned short* __restrict__ W1T,
    const float* __restrict__ W2, unsigned char* __restrict__ W2T8) {
  __shared__ float tile[64][65];
  int b = blockIdx.x;
  if (b < 512) {
    const float* in = (b < 256) ? W1 : W2;
    int R = (b < 256) ? DDIM : HDIM;
    int C = (b < 256) ? HDIM : DDIM;
    int bb = b & 255;
    int nbc = C >> 6;
    int br = bb / nbc, bc = bb % nbc;
    int r0 = br * 64, c0 = bc * 64;
    int tr = threadIdx.x >> 6, tc = threadIdx.x & 63;
    for (int i = 0; i < 16; ++i) {
      int row = i * 4 + tr;
      tile[row][tc] = in[(r0 + row) * C + c0 + tc];
    }
    __syncthreads();
    if (b < 256) {
      for (int i = 0; i < 16; ++i) {
        int row = i * 4 + tr;
        W1T[(c0 + row) * R + r0 + tc] = f32_to_bf16(tile[tc][row]);
      }
    } else {
      for (int i = 0; i < 16; ++i) {
        int row = i * 4 + tr;
        W2T8[(c0 + row) * R + r0 + tc] = f32_to_fp8(tile[tc][row]);
      }
    }
  } else {
    int i = (b - 512) * 256 + threadIdx.x;
    float v = x[i];
    y[i] = v;
    arg[i] = f32_to_bf16(v);
  }
}

// ---- GEMM1: H8 = fp8(tanh(arg[1024,512] @ W1 + b1 + t)) -------------------
// 64x64 tile, BK=128, 4 kt, SINGLE-buffer 32KB, 4 blk/CU, XCD bn-major.
__global__ __launch_bounds__(256, 4) void gemm1_kernel(
    const unsigned short* __restrict__ A,    // arg bf16 [1024,512]
    const unsigned short* __restrict__ Bt,   // W1T bf16 [2048,512]
    const float* __restrict__ b1, float tval,
    unsigned char* __restrict__ H8)          // [1024,2048] fp8
{
  extern __shared__ char ldsbuf[];
  bf16x8* sA = (bf16x8*)ldsbuf;              // 1024 units (16KB)
  bf16x8* sB = (bf16x8*)(ldsbuf + 16384);    // 1024 units (16KB)
  const int K = DDIM;
  int bid = blockIdx.x;
  int lid = (bid & 7) * 64 + (bid >> 3);   // XCD-contiguous logical id
  int bn = lid >> 4;              // 0..31  (W1T panel: 1 XCD each)
  int bm = lid & 15;              // 0..15
  int tid = threadIdx.x;
  int lane = tid & 63;
  int wid = tid >> 6;
  int l15 = lane & 15;
  int l4 = lane >> 4;
  int wm = (wid >> 1) * 32;
  int wn = (wid & 1) * 32;
  int sw = l15 & 7;               // read-side swizzle (row & 7)

  const unsigned short* gA[4];
  const unsigned short* gB[4];
#pragma unroll
  for (int i = 0; i < 4; ++i) {
    int u = tid + i * 256, r = u >> 4, s = u & 15;
    int koff = ((s ^ (r & 7)) * 8);
    gA[i] = A + (size_t)(bm * 64 + r) * K + koff;
    gB[i] = Bt + (size_t)(bn * 64 + r) * K + koff;
  }
  f32x4 acc[2][2] = {};

#pragma unroll 1
  for (int kt = 0; kt < 4; ++kt) {
    int off = kt * 128;
    __syncthreads();               // previous compute done; LDS free
#pragma unroll
    for (int i = 0; i < 4; ++i) {
      async_copy16(gA[i] + off, &sA[tid + i * 256]);
      async_copy16(gB[i] + off, &sB[tid + i * 256]);
    }
    __syncthreads();               // stages landed (vmcnt drained)
#pragma unroll
    for (int ks = 0; ks < 4; ++ks) {
      int kg = (ks * 4 + l4) ^ sw;
      bf16x8 af[2], bfr[2];
#pragma unroll
      for (int i = 0; i < 2; ++i)
        af[i] = sA[(wm + i * 16 + l15) * 16 + kg];
#pragma unroll
      for (int j = 0; j < 2; ++j)
        bfr[j] = sB[(wn + j * 16 + l15) * 16 + kg];
#pragma unroll
      for (int i = 0; i < 2; ++i)
#pragma unroll
        for (int j = 0; j < 2; ++j)
          acc[i][j] = __builtin_amdgcn_mfma_f32_16x16x32_bf16(
              af[i], bfr[j], acc[i][j], 0, 0, 0);
    }
  }
  int row0 = bm * 64 + wm + l4 * 4;
  int col0 = bn * 64 + wn + l15;
  float bias[2];
  for (int j = 0; j < 2; ++j) bias[j] = b1[col0 + j * 16] + tval;
#pragma unroll
  for (int i = 0; i < 2; ++i)
#pragma unroll
    for (int r = 0; r < 4; ++r) {
      unsigned char* Hrow = H8 + (size_t)(row0 + i * 16 + r) * HDIM + col0;
      Hrow[0]  = f32_to_fp8(tanh_fast(acc[i][0][r] + bias[0]));
      Hrow[16] = f32_to_fp8(tanh_fast(acc[i][1][r] + bias[1]));
    }
}

// ---- GEMM2 (fp8) + RK4: k = H @ W2T' + b2, then RK4 state update ----------
// 32x32 tile, FULL K=2048, 4 waves x K-window 512, BK=128 fp8, 4 kt,
// SINGLE-buffer 32KB, 4 blk/CU, XCD bm-major. fp32 LDS reduce + fused RK4.
// mode 0: kacc = k;            arg = bf16(y + dt/2*k)
// mode 1: kacc += 2k;          arg = bf16(y + dt/2*k)
// mode 2: kacc += 2k;          arg = bf16(y + dt*k)
// mode 3: y += dt/6*(kacc+k);  arg = bf16(y_new)
__global__ __launch_bounds__(256, 4) void gemm2rk4_kernel(
    const unsigned char* __restrict__ A8,    // H fp8 [1024,2048]
    const unsigned char* __restrict__ B8,    // W2T fp8 [512,2048]
    const float* __restrict__ b2,
    float* __restrict__ y, float* __restrict__ kacc,
    unsigned short* __restrict__ arg, int mode, float dt)
{
  extern __shared__ char ldsbuf[];
  char* sA8 = ldsbuf;              // 16KB
  char* sB8 = ldsbuf + 16384;      // 16KB
  const int K = HDIM;
  int bid = blockIdx.x;
  int lid = (bid & 7) * 64 + (bid >> 3);   // XCD-contiguous logical id
  int bm = lid >> 4;              // 0..31 (Hbuf panel: 1 XCD each)
  int bn = lid & 15;              // 0..15
  int tid = threadIdx.x;
  int lane = tid & 63;
  int wid = tid >> 6;             // wave = K-window 0..3
  int l15 = lane & 15;
  int l4 = lane >> 4;
  int sw = l15 & 7;

  // staging: 1024 16B-units per matrix per kt (4/thread)
  // unit u -> (win=u>>8, row=(u>>3)&31, slot16=u&7); row = 128B (BK=128 fp8)
  const unsigned char* gA[4];
  const unsigned char* gB[4];
#pragma unroll
  for (int i = 0; i < 4; ++i) {
    int u = tid + i * 256;
    int w = u >> 8, r = (u >> 3) & 31, sl = u & 7;
    int koff = w * 512 + ((sl ^ (r & 7)) * 16);
    gA[i] = A8 + (size_t)(bm * 32 + r) * K + koff;
    gB[i] = B8 + (size_t)(bn * 32 + r) * K + koff;
  }
  f32x4 acc[2][2] = {};

#pragma unroll 1
  for (int kt = 0; kt < 4; ++kt) {
    int off = kt * 128;            // 128 fp8 = 128 B
    __syncthreads();               // previous compute done; LDS free
#pragma unroll
    for (int i = 0; i < 4; ++i) {
      async_copy16(gA[i] + off, sA8 + (tid + i * 256) * 16);
      async_copy16(gB[i] + off, sB8 + (tid + i * 256) * 16);
    }
    __syncthreads();               // stages landed
#pragma unroll
    for (int ks = 0; ks < 4; ++ks) {
      // lane wants k-bytes [ks*32 + l4*8, +8) of its window's 128B row:
      // 16B-slot c = ks*2 + (l4>>1) (XOR-swizzled), +8B if l4 odd.
      int soff = (((ks * 2 + (l4 >> 1)) ^ sw) * 16) + (l4 & 1) * 8;
      long af[2], bfr[2];
#pragma unroll
      for (int i = 0; i < 2; ++i)
        af[i] = *(const long*)(sA8 + wid * 4096 + (i * 16 + l15) * 128 + soff);
#pragma unroll
      for (int j = 0; j < 2; ++j)
        bfr[j] = *(const long*)(sB8 + wid * 4096 + (j * 16 + l15) * 128 + soff);
#pragma unroll
      for (int i = 0; i < 2; ++i)
#pragma unroll
        for (int j = 0; j < 2; ++j)
          acc[i][j] = __builtin_amdgcn_mfma_f32_16x16x32_fp8_fp8(
              af[i], bfr[j], acc[i][j], 0, 0, 0);
    }
  }

  // ---- fp32 reduction over the 4 K-windows (overlay on dead staging) ----
  __syncthreads();                         // all staging reads complete
  float* red = (float*)ldsbuf;             // [4][32][36] f32 = 18KB (< 32KB)
#pragma unroll
  for (int i = 0; i < 2; ++i)
#pragma unroll
    for (int j = 0; j < 2; ++j)
#pragma unroll
      for (int q = 0; q < 4; ++q) {
        int row = i * 16 + l4 * 4 + q;
        int col = j * 16 + l15;
        red[(wid * 32 + row) * 36 + col] = acc[i][j][q];
      }
  __syncthreads();

  // ---- RK4 epilogue: 256 thr x 4 elems over the 32x32 tile ----
  int row = tid >> 3;                      // 0..31
  int c4 = (tid & 7) * 4;                  // 0..28
  float4 s0 = *(float4*)&red[(0 * 32 + row) * 36 + c4];
  float4 s1 = *(float4*)&red[(1 * 32 + row) * 36 + c4];
  float4 s2 = *(float4*)&red[(2 * 32 + row) * 36 + c4];
  float4 s3 = *(float4*)&red[(3 * 32 + row) * 36 + c4];
  int grow = bm * 32 + row;
  int gcol = bn * 32 + c4;
  size_t off = (size_t)grow * DDIM + gcol;
  float4 bb = *(const float4*)(b2 + gcol);
  float4 k;
  k.x = s0.x + s1.x + s2.x + s3.x + bb.x;
  k.y = s0.y + s1.y + s2.y + s3.y + bb.y;
  k.z = s0.z + s1.z + s2.z + s3.z + bb.z;
  k.w = s0.w + s1.w + s2.w + s3.w + bb.w;
  float4 yv = *(const float4*)(y + off);
  float hh = 0.5f * dt;
  float sx = dt * (1.0f / 6.0f);
  float4 argv;
  if (mode == 0) {
    *(float4*)(kacc + off) = k;
    argv.x = yv.x + hh * k.x; argv.y = yv.y + hh * k.y;
    argv.z = yv.z + hh * k.z; argv.w = yv.w + hh * k.w;
  } else if (mode == 1) {
    float4 ka = *(const float4*)(kacc + off);
    ka.x += 2.0f * k.x; ka.y += 2.0f * k.y; ka.z += 2.0f * k.z; ka.w += 2.0f * k.w;
    *(float4*)(kacc + off) = ka;
    argv.x = yv.x + hh * k.x; argv.y = yv.y + hh * k.y;
    argv.z = yv.z + hh * k.z; argv.w = yv.w + hh * k.w;
  } else if (mode == 2) {
    float4 ka = *(const float4*)(kacc + off);
    ka.x += 2.0f * k.x; ka.y += 2.0f * k.y; ka.z += 2.0f * k.z; ka.w += 2.0f * k.w;
    *(float4*)(kacc + off) = ka;
    argv.x = yv.x + dt * k.x; argv.y = yv.y + dt * k.y;
    argv.z = yv.z + dt * k.z; argv.w = yv.w + dt * k.w;
  } else {
    float4 ka = *(const float4*)(kacc + off);
    argv.x = yv.x + sx * (ka.x + k.x); argv.y = yv.y + sx * (ka.y + k.y);
    argv.z = yv.z + sx * (ka.z + k.z); argv.w = yv.w + sx * (ka.w + k.w);
    *(float4*)(y + off) = argv;
  }
  ushort4 av;
  av.x = f32_to_bf16(argv.x); av.y = f32_to_bf16(argv.y);
  av.z = f32_to_bf16(argv.z); av.w = f32_to_bf16(argv.w);
  *(ushort4*)(arg + off) = av;
}

extern "C" void kernel_launch(void* const* d_in, const int* in_sizes, int n_in,
                              void* d_out, int out_size, void* d_ws, size_t ws_size,
                              hipStream_t stream) {
  (void)in_sizes; (void)n_in; (void)out_size; (void)ws_size;
  const float* x  = (const float*)d_in[0];   // [1024,512]
  const float* W1 = (const float*)d_in[1];   // [512,2048]
  const float* b1 = (const float*)d_in[2];   // [2048]
  const float* W2 = (const float*)d_in[3];   // [2048,512]
  const float* b2 = (const float*)d_in[4];   // [512]
  float* y = (float*)d_out;                  // fp32 state lives in d_out

  char* ws = (char*)d_ws;
  unsigned short* W1T  = (unsigned short*)(ws);                    // 2MB  [2048,512] bf16
  unsigned char*  W2T8 = (unsigned char*)(ws + (2u << 20));        // 1MB  [512,2048] fp8
  unsigned char*  H8   = (unsigned char*)(ws + (4u << 20));        // 2MB  [1024,2048] fp8
  unsigned short* arg  = (unsigned short*)(ws + (8u << 20));       // 1MB  [1024,512] bf16
  float*          kacc = (float*)(ws + (9u << 20));                // 2MB  [1024,512] f32

  hipFuncSetAttribute((const void*)gemm1_kernel,
                      hipFuncAttributeMaxDynamicSharedMemorySize, GEMM_LDS);
  hipFuncSetAttribute((const void*)gemm2rk4_kernel,
                      hipFuncAttributeMaxDynamicSharedMemorySize, GEMM2_LDS);

  setup_kernel<<<2560, 256, 0, stream>>>(x, y, arg, W1, W1T, W2, W2T8);

  const float dt = 1.0f / 16.0f;
  for (int n = 0; n < 16; ++n) {
    float t0 = dt * (float)n;
    const float ts[4] = {t0, t0 + 0.5f * dt, t0 + 0.5f * dt, t0 + dt};
    for (int s = 0; s < 4; ++s) {
      gemm1_kernel<<<512, 256, GEMM_LDS, stream>>>(arg, W1T, b1, ts[s], H8);
      gemm2rk4_kernel<<<512, 256, GEMM2_LDS, stream>>>(H8, W2T8, b2, y, kacc, arg, s, dt);
    }
  }
}

// Round 13
// 861.861 us; speedup vs baseline: 1.1336x; 1.1336x over previous
//
#include <hip/hip_runtime.h>
#include <cstdint>

// ODEBlock: 16 RK4 steps of f(t,y) = tanh(y@W1 + b1 + t) @ W2 + b2
// B=1024 (M), D=512, H=2048. gemm1 bf16 MFMA; gemm2 fp8-e4m3 MFMA.
// R25 = R23 (877us best) GEMM cores exactly + R24's merged setup kernel.
// R24 post-mortem (+100us): single-buffer@4blk/CU loses to dbuf@2blk/CU --
// within-block dbuf prefetch is load-bearing; cross-block TLP does not
// substitute (serialized staging phases contend for L2 instead of
// interleaving). Decision rule fired -> revert cores, keep the independent
// setup merge (3 dispatches -> 1).
// Proven stack: fp8 gemm2 (R23 -213us), XCD swizzles (R20 -55us), fused
// RK4 epilogue (R19 -104us), dbuf 64KB 2blk/CU cores (R13/R23).
// Closed lines: mega-kernel (R14-R22: cross-block visibility needs full
// acq/rel wb/inv; per-access protocols all fail absmax 1.9336); precision
// levers (absmax 0.1016 vs 0.10875 threshold, 6% margin); single-buffer
// occupancy trade (R24). Dispatches: 129.

typedef __bf16 bf16x8 __attribute__((ext_vector_type(8)));
typedef float f32x4 __attribute__((ext_vector_type(4)));

#define AS1 __attribute__((address_space(1)))
#define AS3 __attribute__((address_space(3)))

#define MDIM 1024
#define DDIM 512
#define HDIM 2048

#define GEMM_LDS (64 * 1024)    // gemm1: sA 2x16KB + sB 2x16KB (bf16 dbuf)
#define GEMM2_LDS (64 * 1024)   // gemm2rk4: sA8 2x16KB + sB8 2x16KB (fp8 dbuf)

__device__ __forceinline__ void async_copy16(const void* g, void* lds) {
  __builtin_amdgcn_global_load_lds((const AS1 void*)g, (AS3 void*)lds, 16, 0, 0);
}

__device__ __forceinline__ unsigned short f32_to_bf16(float f) {
  union { float f; unsigned u; } c; c.f = f;
  unsigned u = c.u + 0x7FFFu + ((c.u >> 16) & 1u);   // RNE
  return (unsigned short)(u >> 16);
}

// f32 -> fp8 e4m3 (gfx950 native); duplicated src = byte-order-immune.
__device__ __forceinline__ unsigned char f32_to_fp8(float v) {
  unsigned p;
  asm("v_cvt_pk_fp8_f32 %0, %1, %1" : "=v"(p) : "v"(v));
  return (unsigned char)(p & 0xFF);
}

__device__ __forceinline__ float tanh_fast(float x) {
  float a = __builtin_fabsf(x);
  float e = __expf(-2.0f * a);                        // in (0,1], no overflow
  float r = (1.0f - e) * __builtin_amdgcn_rcpf(1.0f + e);
  return __builtin_copysignf(r, x);
}

// ---- merged setup: W1->W1T bf16, W2->W2T8 fp8, y/arg init -----------------
// blocks 0..255: transpose W1 [512,2048] -> W1T bf16 [2048,512]
// blocks 256..511: transpose W2 [2048,512] -> W2T8 fp8 [512,2048]
// blocks 512..2559: y = x, arg = bf16(x)
__global__ __launch_bounds__(256) void setup_kernel(
    const float* __restrict__ x, float* __restrict__ y,
    unsigned short* __restrict__ arg,
    const float* __restrict__ W1, unsigned short* __restrict__ W1T,
    const float* __restrict__ W2, unsigned char* __restrict__ W2T8) {
  __shared__ float tile[64][65];
  int b = blockIdx.x;
  if (b < 512) {
    const float* in = (b < 256) ? W1 : W2;
    int R = (b < 256) ? DDIM : HDIM;
    int C = (b < 256) ? HDIM : DDIM;
    int bb = b & 255;
    int nbc = C >> 6;
    int br = bb / nbc, bc = bb % nbc;
    int r0 = br * 64, c0 = bc * 64;
    int tr = threadIdx.x >> 6, tc = threadIdx.x & 63;
    for (int i = 0; i < 16; ++i) {
      int row = i * 4 + tr;
      tile[row][tc] = in[(r0 + row) * C + c0 + tc];
    }
    __syncthreads();
    if (b < 256) {
      for (int i = 0; i < 16; ++i) {
        int row = i * 4 + tr;
        W1T[(c0 + row) * R + r0 + tc] = f32_to_bf16(tile[tc][row]);
      }
    } else {
      for (int i = 0; i < 16; ++i) {
        int row = i * 4 + tr;
        W2T8[(c0 + row) * R + r0 + tc] = f32_to_fp8(tile[tc][row]);
      }
    }
  } else {
    int i = (b - 512) * 256 + threadIdx.x;
    float v = x[i];
    y[i] = v;
    arg[i] = f32_to_bf16(v);
  }
}

// ---- GEMM1: H8 = fp8(tanh(arg[1024,512] @ W1 + b1 + t)) -------------------
// R23-proven: 64x64, BK=128, 4 kt, dbuf 64KB, 2 blk/CU, XCD bn-major.
__global__ __launch_bounds__(256, 2) void gemm1_kernel(
    const unsigned short* __restrict__ A,    // arg bf16 [1024,512]
    const unsigned short* __restrict__ Bt,   // W1T bf16 [2048,512]
    const float* __restrict__ b1, float tval,
    unsigned char* __restrict__ H8)          // [1024,2048] fp8
{
  extern __shared__ char ldsbuf[];
  bf16x8* sA = (bf16x8*)ldsbuf;              // 2 x 1024 units (32KB)
  bf16x8* sB = (bf16x8*)(ldsbuf + 32768);    // 2 x 1024 units (32KB)
  const int K = DDIM;
  const int NITER = 4;            // 512 / 128
  int bid = blockIdx.x;
  int lid = (bid & 7) * 64 + (bid >> 3);   // XCD-contiguous logical id
  int bn = lid >> 4;              // 0..31  (W1T panel: 1 XCD each)
  int bm = lid & 15;              // 0..15
  int tid = threadIdx.x;
  int lane = tid & 63;
  int wid = tid >> 6;
  int l15 = lane & 15;
  int l4 = lane >> 4;
  int wm = (wid >> 1) * 32;
  int wn = (wid & 1) * 32;
  int sw = l15 & 7;               // read-side swizzle (row & 7)

  const unsigned short* gA[4];
  const unsigned short* gB[4];
#pragma unroll
  for (int i = 0; i < 4; ++i) {
    int u = tid + i * 256, r = u >> 4, s = u & 15;
    int koff = ((s ^ (r & 7)) * 8);
    gA[i] = A + (size_t)(bm * 64 + r) * K + koff;
    gB[i] = Bt + (size_t)(bn * 64 + r) * K + koff;
  }
  f32x4 acc[2][2] = {};

#pragma unroll
  for (int i = 0; i < 4; ++i) {
    async_copy16(gA[i], &sA[tid + i * 256]);
    async_copy16(gB[i], &sB[tid + i * 256]);
  }

#pragma unroll 1
  for (int kt = 0; kt < NITER; ++kt) {
    int cur = kt & 1;
    __syncthreads();
    if (kt + 1 < NITER) {
      int nxt = cur ^ 1;
      int off = (kt + 1) * 128;
#pragma unroll
      for (int i = 0; i < 4; ++i) {
        async_copy16(gA[i] + off, &sA[nxt * 1024 + tid + i * 256]);
        async_copy16(gB[i] + off, &sB[nxt * 1024 + tid + i * 256]);
      }
    }
#pragma unroll
    for (int ks = 0; ks < 4; ++ks) {
      int kg = (ks * 4 + l4) ^ sw;
      bf16x8 af[2], bfr[2];
#pragma unroll
      for (int i = 0; i < 2; ++i)
        af[i] = sA[cur * 1024 + (wm + i * 16 + l15) * 16 + kg];
#pragma unroll
      for (int j = 0; j < 2; ++j)
        bfr[j] = sB[cur * 1024 + (wn + j * 16 + l15) * 16 + kg];
#pragma unroll
      for (int i = 0; i < 2; ++i)
#pragma unroll
        for (int j = 0; j < 2; ++j)
          acc[i][j] = __builtin_amdgcn_mfma_f32_16x16x32_bf16(
              af[i], bfr[j], acc[i][j], 0, 0, 0);
    }
  }
  int row0 = bm * 64 + wm + l4 * 4;
  int col0 = bn * 64 + wn + l15;
  float bias[2];
  for (int j = 0; j < 2; ++j) bias[j] = b1[col0 + j * 16] + tval;
#pragma unroll
  for (int i = 0; i < 2; ++i)
#pragma unroll
    for (int r = 0; r < 4; ++r) {
      unsigned char* Hrow = H8 + (size_t)(row0 + i * 16 + r) * HDIM + col0;
      Hrow[0]  = f32_to_fp8(tanh_fast(acc[i][0][r] + bias[0]));
      Hrow[16] = f32_to_fp8(tanh_fast(acc[i][1][r] + bias[1]));
    }
}

// ---- GEMM2 (fp8) + RK4: k = H @ W2T' + b2, then RK4 state update ----------
// R23-proven: 32x32 full-K, 4 waves x K-window 512, BK=128 fp8, 4 kt,
// dbuf 64KB, 2 blk/CU, XCD bm-major. fp32 LDS reduce + fused RK4.
// mode 0: kacc = k;            arg = bf16(y + dt/2*k)
// mode 1: kacc += 2k;          arg = bf16(y + dt/2*k)
// mode 2: kacc += 2k;          arg = bf16(y + dt*k)
// mode 3: y += dt/6*(kacc+k);  arg = bf16(y_new)
__global__ __launch_bounds__(256, 2) void gemm2rk4_kernel(
    const unsigned char* __restrict__ A8,    // H fp8 [1024,2048]
    const unsigned char* __restrict__ B8,    // W2T fp8 [512,2048]
    const float* __restrict__ b2,
    float* __restrict__ y, float* __restrict__ kacc,
    unsigned short* __restrict__ arg, int mode, float dt)
{
  extern __shared__ char ldsbuf[];
  char* sA8 = ldsbuf;              // 2 x 16KB
  char* sB8 = ldsbuf + 32768;      // 2 x 16KB
  const int K = HDIM;
  int bid = blockIdx.x;
  int lid = (bid & 7) * 64 + (bid >> 3);   // XCD-contiguous logical id
  int bm = lid >> 4;              // 0..31 (Hbuf panel: 1 XCD each)
  int bn = lid & 15;              // 0..15
  int tid = threadIdx.x;
  int lane = tid & 63;
  int wid = tid >> 6;             // wave = K-window 0..3
  int l15 = lane & 15;
  int l4 = lane >> 4;
  int sw = l15 & 7;

  // staging: 1024 16B-units per matrix per kt (4/thread)
  // unit u -> (win=u>>8, row=(u>>3)&31, slot16=u&7); row = 128B (BK=128 fp8)
  const unsigned char* gA[4];
  const unsigned char* gB[4];
#pragma unroll
  for (int i = 0; i < 4; ++i) {
    int u = tid + i * 256;
    int w = u >> 8, r = (u >> 3) & 31, sl = u & 7;
    int koff = w * 512 + ((sl ^ (r & 7)) * 16);
    gA[i] = A8 + (size_t)(bm * 32 + r) * K + koff;
    gB[i] = B8 + (size_t)(bn * 32 + r) * K + koff;
  }
  f32x4 acc[2][2] = {};

#pragma unroll
  for (int i = 0; i < 4; ++i) {
    async_copy16(gA[i], sA8 + (tid + i * 256) * 16);
    async_copy16(gB[i], sB8 + (tid + i * 256) * 16);
  }

#pragma unroll 1
  for (int kt = 0; kt < 4; ++kt) {
    int cur = kt & 1;
    __syncthreads();
    if (kt + 1 < 4) {
      int nxt = cur ^ 1;
      int off = (kt + 1) * 128;            // 128 fp8 = 128 B
#pragma unroll
      for (int i = 0; i < 4; ++i) {
        async_copy16(gA[i] + off, sA8 + nxt * 16384 + (tid + i * 256) * 16);
        async_copy16(gB[i] + off, sB8 + nxt * 16384 + (tid + i * 256) * 16);
      }
    }
#pragma unroll
    for (int ks = 0; ks < 4; ++ks) {
      // lane wants k-bytes [ks*32 + l4*8, +8) of its window's 128B row:
      // 16B-slot c = ks*2 + (l4>>1) (XOR-swizzled), +8B if l4 odd.
      int soff = (((ks * 2 + (l4 >> 1)) ^ sw) * 16) + (l4 & 1) * 8;
      long af[2], bfr[2];
#pragma unroll
      for (int i = 0; i < 2; ++i)
        af[i] = *(const long*)(sA8 + cur * 16384 + wid * 4096 +
                               (i * 16 + l15) * 128 + soff);
#pragma unroll
      for (int j = 0; j < 2; ++j)
        bfr[j] = *(const long*)(sB8 + cur * 16384 + wid * 4096 +
                                (j * 16 + l15) * 128 + soff);
#pragma unroll
      for (int i = 0; i < 2; ++i)
#pragma unroll
        for (int j = 0; j < 2; ++j)
          acc[i][j] = __builtin_amdgcn_mfma_f32_16x16x32_fp8_fp8(
              af[i], bfr[j], acc[i][j], 0, 0, 0);
    }
  }

  // ---- fp32 reduction over the 4 K-windows (overlay on dead staging) ----
  __syncthreads();                         // all staging reads complete
  float* red = (float*)ldsbuf;             // [4][32][36] f32 = 18KB
#pragma unroll
  for (int i = 0; i < 2; ++i)
#pragma unroll
    for (int j = 0; j < 2; ++j)
#pragma unroll
      for (int q = 0; q < 4; ++q) {
        int row = i * 16 + l4 * 4 + q;
        int col = j * 16 + l15;
        red[(wid * 32 + row) * 36 + col] = acc[i][j][q];
      }
  __syncthreads();

  // ---- RK4 epilogue: 256 thr x 4 elems over the 32x32 tile ----
  int row = tid >> 3;                      // 0..31
  int c4 = (tid & 7) * 4;                  // 0..28
  float4 s0 = *(float4*)&red[(0 * 32 + row) * 36 + c4];
  float4 s1 = *(float4*)&red[(1 * 32 + row) * 36 + c4];
  float4 s2 = *(float4*)&red[(2 * 32 + row) * 36 + c4];
  float4 s3 = *(float4*)&red[(3 * 32 + row) * 36 + c4];
  int grow = bm * 32 + row;
  int gcol = bn * 32 + c4;
  size_t off = (size_t)grow * DDIM + gcol;
  float4 bb = *(const float4*)(b2 + gcol);
  float4 k;
  k.x = s0.x + s1.x + s2.x + s3.x + bb.x;
  k.y = s0.y + s1.y + s2.y + s3.y + bb.y;
  k.z = s0.z + s1.z + s2.z + s3.z + bb.z;
  k.w = s0.w + s1.w + s2.w + s3.w + bb.w;
  float4 yv = *(const float4*)(y + off);
  float hh = 0.5f * dt;
  float sx = dt * (1.0f / 6.0f);
  float4 argv;
  if (mode == 0) {
    *(float4*)(kacc + off) = k;
    argv.x = yv.x + hh * k.x; argv.y = yv.y + hh * k.y;
    argv.z = yv.z + hh * k.z; argv.w = yv.w + hh * k.w;
  } else if (mode == 1) {
    float4 ka = *(const float4*)(kacc + off);
    ka.x += 2.0f * k.x; ka.y += 2.0f * k.y; ka.z += 2.0f * k.z; ka.w += 2.0f * k.w;
    *(float4*)(kacc + off) = ka;
    argv.x = yv.x + hh * k.x; argv.y = yv.y + hh * k.y;
    argv.z = yv.z + hh * k.z; argv.w = yv.w + hh * k.w;
  } else if (mode == 2) {
    float4 ka = *(const float4*)(kacc + off);
    ka.x += 2.0f * k.x; ka.y += 2.0f * k.y; ka.z += 2.0f * k.z; ka.w += 2.0f * k.w;
    *(float4*)(kacc + off) = ka;
    argv.x = yv.x + dt * k.x; argv.y = yv.y + dt * k.y;
    argv.z = yv.z + dt * k.z; argv.w = yv.w + dt * k.w;
  } else {
    float4 ka = *(const float4*)(kacc + off);
    argv.x = yv.x + sx * (ka.x + k.x); argv.y = yv.y + sx * (ka.y + k.y);
    argv.z = yv.z + sx * (ka.z + k.z); argv.w = yv.w + sx * (ka.w + k.w);
    *(float4*)(y + off) = argv;
  }
  ushort4 av;
  av.x = f32_to_bf16(argv.x); av.y = f32_to_bf16(argv.y);
  av.z = f32_to_bf16(argv.z); av.w = f32_to_bf16(argv.w);
  *(ushort4*)(arg + off) = av;
}

extern "C" void kernel_launch(void* const* d_in, const int* in_sizes, int n_in,
                              void* d_out, int out_size, void* d_ws, size_t ws_size,
                              hipStream_t stream) {
  (void)in_sizes; (void)n_in; (void)out_size; (void)ws_size;
  const float* x  = (const float*)d_in[0];   // [1024,512]
  const float* W1 = (const float*)d_in[1];   // [512,2048]
  const float* b1 = (const float*)d_in[2];   // [2048]
  const float* W2 = (const float*)d_in[3];   // [2048,512]
  const float* b2 = (const float*)d_in[4];   // [512]
  float* y = (float*)d_out;                  // fp32 state lives in d_out

  char* ws = (char*)d_ws;
  unsigned short* W1T  = (unsigned short*)(ws);                    // 2MB  [2048,512] bf16
  unsigned char*  W2T8 = (unsigned char*)(ws + (2u << 20));        // 1MB  [512,2048] fp8
  unsigned char*  H8   = (unsigned char*)(ws + (4u << 20));        // 2MB  [1024,2048] fp8
  unsigned short* arg  = (unsigned short*)(ws + (8u << 20));       // 1MB  [1024,512] bf16
  float*          kacc = (float*)(ws + (9u << 20));                // 2MB  [1024,512] f32

  hipFuncSetAttribute((const void*)gemm1_kernel,
                      hipFuncAttributeMaxDynamicSharedMemorySize, GEMM_LDS);
  hipFuncSetAttribute((const void*)gemm2rk4_kernel,
                      hipFuncAttributeMaxDynamicSharedMemorySize, GEMM2_LDS);

  setup_kernel<<<2560, 256, 0, stream>>>(x, y, arg, W1, W1T, W2, W2T8);

  const float dt = 1.0f / 16.0f;
  for (int n = 0; n < 16; ++n) {
    float t0 = dt * (float)n;
    const float ts[4] = {t0, t0 + 0.5f * dt, t0 + 0.5f * dt, t0 + dt};
    for (int s = 0; s < 4; ++s) {
      gemm1_kernel<<<512, 256, GEMM_LDS, stream>>>(arg, W1T, b1, ts[s], H8);
      gemm2rk4_kernel<<<512, 256, GEMM2_LDS, stream>>>(H8, W2T8, b2, y, kacc, arg, s, dt);
    }
  }
}